// Round 6
// baseline (192.487 us; speedup 1.0000x reference)
//
#include <hip/hip_runtime.h>

#define HID 896
#define NH 14
#define NKV 2
#define NREP 7
#define SEQ 2048
#define BT 2
#define NTOK (BT*SEQ)
#define CSCALE 0.18033688011112042f   // (1/8) * log2(e), folded into Q at projection

typedef __attribute__((ext_vector_type(8))) short bf16x8;
typedef __attribute__((ext_vector_type(8))) unsigned short u16x8;
typedef __attribute__((ext_vector_type(4))) float fx4;
typedef __attribute__((ext_vector_type(4))) short s16x4;
typedef _Float16 f16x4 __attribute__((ext_vector_type(4)));
typedef __fp16 fp16x2 __attribute__((ext_vector_type(2)));

__device__ __forceinline__ unsigned short f2b(float x){
  union { float f; unsigned u; } a; a.f = x;
  unsigned r = a.u + 0x7FFFu + ((a.u >> 16) & 1u);   // RNE
  return (unsigned short)(r >> 16);
}
__device__ __forceinline__ unsigned short f2h(float x){
  union { _Float16 h; unsigned short u; } a; a.h = (_Float16)x; return a.u;
}

// async global->LDS, 16B/lane: LDS dst = wave-uniform base + lane*16 (m97 pattern)
__device__ __forceinline__ void gll16(const unsigned short* g, short* lds){
  __builtin_amdgcn_global_load_lds(
      (const __attribute__((address_space(1))) unsigned int*)(const void*)g,
      (__attribute__((address_space(3))) unsigned int*)(void*)lds, 16, 0, 0);
}

// ------- fp32->bf16 convert (weights only; hidden is folded into qkv A-staging) -------
__global__ __launch_bounds__(256) void cvt_kernel(
    const float* __restrict__ s0, const float* __restrict__ s1,
    const float* __restrict__ s2, const float* __restrict__ s3,
    unsigned short* __restrict__ d0, unsigned short* __restrict__ d1,
    unsigned short* __restrict__ d2, unsigned short* __restrict__ d3,
    int c0, int c1, int c2, int c3,
    float2* __restrict__ tab)
{
  if (blockIdx.y == 4){
    for (int i = blockIdx.x*256 + threadIdx.x; i < SEQ*32; i += gridDim.x*256){
      int s = i >> 5, d = i & 31;
      float f = (float)s * exp2f(-(float)d * 0.62286151779138041f);
      float sv, cv; sincosf(f, &sv, &cv);
      tab[i] = make_float2(cv, sv);
    }
    return;
  }
  const float* s; unsigned short* d; int c;
  switch (blockIdx.y){
    case 0: s=s0; d=d0; c=c0; break;
    case 1: s=s1; d=d1; c=c1; break;
    case 2: s=s2; d=d2; c=c2; break;
    default: s=s3; d=d3; c=c3; break;
  }
  for (int i = (blockIdx.x*256 + threadIdx.x)*8; i < c; i += gridDim.x*2048){
    float4 a = *(const float4*)(s + i);
    float4 b = *(const float4*)(s + i + 4);
    u16x8 o;
    o[0]=f2b(a.x); o[1]=f2b(a.y); o[2]=f2b(a.z); o[3]=f2b(a.w);
    o[4]=f2b(b.x); o[5]=f2b(b.y); o[6]=f2b(b.z); o[7]=f2b(b.w);
    *(u16x8*)(d + i) = o;
  }
}

// ---------------- QKV projection GEMM: A from fp32 hidden (reg-staged cvt), B via gll16 ----------------
__global__ __launch_bounds__(256) void qkv_gemm_kernel(
    const float* __restrict__ Ahid, const unsigned short* __restrict__ Bw,
    const float* __restrict__ bq, const float* __restrict__ bk, const float* __restrict__ bv,
    const int* __restrict__ pos, const float2* __restrict__ tab,
    unsigned short* __restrict__ qo, unsigned short* __restrict__ ko,
    unsigned short* __restrict__ vt)
{
  __shared__ short As[2][64*64];     // 16 KB
  __shared__ short Bs[2][128*64];    // 32 KB
  const int tid = threadIdx.x;
  const int bm = blockIdx.x, bn = blockIdx.y;
  const int w = tid >> 6, l = tid & 63, l15 = l & 15, q4 = l >> 4;
  const int wm = w >> 1, wn = w & 1;
  const int lr = l >> 3;                 // row-in-chunk 0..7
  const int cbg = (l & 7) ^ lr;          // swizzled global 16B-block
  const int sw = l15 & 7;                // frag-read swizzle key

  fx4 acc[2][4] = {};

  const float*          Ag = Ahid + (size_t)(bm*64)*HID;
  const unsigned short* Bg = Bw   + (size_t)(bn*128)*HID;

  float4 Areg[2][2];
  auto loadA = [&](int kt){
    const int kc = kt*64 + cbg*8;
#pragma unroll
    for (int p = 0; p < 2; p++){
      const float* src = Ag + (size_t)((p*4 + w)*8 + lr)*HID + kc;
      Areg[p][0] = *(const float4*)(src);
      Areg[p][1] = *(const float4*)(src + 4);
    }
  };
  auto storeA = [&](int buf){
#pragma unroll
    for (int p = 0; p < 2; p++){
      int c = p*4 + w;
      u16x8 o;
      o[0]=f2b(Areg[p][0].x); o[1]=f2b(Areg[p][0].y);
      o[2]=f2b(Areg[p][0].z); o[3]=f2b(Areg[p][0].w);
      o[4]=f2b(Areg[p][1].x); o[5]=f2b(Areg[p][1].y);
      o[6]=f2b(Areg[p][1].z); o[7]=f2b(Areg[p][1].w);
      *(u16x8*)&As[buf][c*512 + l*8] = o;
    }
  };
  auto issueB = [&](int kt, int buf){
    const int kc = kt*64 + cbg*8;
#pragma unroll
    for (int p = 0; p < 4; p++){
      int c = p*4 + w;
      gll16(Bg + (size_t)(c*8 + lr)*HID + kc, &Bs[buf][c*512]);
    }
  };

  issueB(0, 0);
  loadA(0);
  for (int kt = 0; kt < 14; kt++){
    const int cur = kt & 1;
    storeA(cur);                         // implicit vmcnt drain: A(kt) + older B(kt) landed
    if (kt < 13){
      issueB(kt+1, cur^1);
      loadA(kt+1);                       // in flight across this iter's compute
    }
    asm volatile("s_waitcnt lgkmcnt(0)\n\ts_barrier" ::: "memory");
#pragma unroll
    for (int ks = 0; ks < 2; ks++){
      bf16x8 af[2], bf[4];
#pragma unroll
      for (int mt = 0; mt < 2; mt++){
        int r = wm*32 + mt*16 + l15;
        af[mt] = *(bf16x8*)&As[cur][r*64 + ((ks*4 + q4) ^ sw)*8];
      }
#pragma unroll
      for (int nt = 0; nt < 4; nt++){
        int r = wn*64 + nt*16 + l15;
        bf[nt] = *(bf16x8*)&Bs[cur][r*64 + ((ks*4 + q4) ^ sw)*8];
      }
#pragma unroll
      for (int mt = 0; mt < 2; mt++)
#pragma unroll
        for (int nt = 0; nt < 4; nt++)
          acc[mt][nt] = __builtin_amdgcn_mfma_f32_16x16x32_bf16(af[mt], bf[nt], acc[mt][nt], 0,0,0);
    }
    asm volatile("s_barrier" ::: "memory");                  // buf[cur] free for kt+2 staging
  }

  const int hu = bn*2 + wn;
  const float* bias; int kind, hloc;
  if (hu < NH)      { bias = bq + hu*64;      kind = 0; hloc = hu; }
  else if (hu < 16) { bias = bk + (hu-NH)*64; kind = 1; hloc = hu-NH; }
  else              { bias = bv + (hu-16)*64; kind = 2; hloc = hu-16; }
  float bl[4];
#pragma unroll
  for (int nt = 0; nt < 4; nt++) bl[nt] = bias[nt*16 + l15];

  if (kind == 2){
#pragma unroll
    for (int mt = 0; mt < 2; mt++)
#pragma unroll
      for (int j = 0; j < 4; j++){
        int grow = bm*64 + wm*32 + mt*16 + q4*4 + j;
        int b = grow >> 11, s = grow & (SEQ-1);
        int tile = s >> 6, key = s & 63;
        unsigned short* dst = vt + (size_t)(((b*NKV + hloc)*(SEQ/64) + tile)*4096);
#pragma unroll
        for (int nt = 0; nt < 4; nt++)
          dst[(nt*16 + l15)*64 + key] = f2h(acc[mt][nt][j] + bl[nt]);
      }
  } else {
    const float qs = (kind == 0) ? CSCALE : 1.0f;
#pragma unroll
    for (int mt = 0; mt < 2; mt++)
#pragma unroll
      for (int j = 0; j < 4; j++){
        int grow = bm*64 + wm*32 + mt*16 + q4*4 + j;
        int b = grow >> 11, s = grow & (SEQ-1);
        int p = pos[grow];
        const float2* rp = tab + p*32 + l15;
        float2 cs0 = rp[0], cs1 = rp[16];
        unsigned short* dst = (kind == 0)
            ? qo + ((size_t)(b*NH  + hloc)*SEQ + s)*64
            : ko + ((size_t)(b*NKV + hloc)*SEQ + s)*64;
        float x1 = acc[mt][0][j] + bl[0], x2 = acc[mt][2][j] + bl[2];
        float y1 = acc[mt][1][j] + bl[1], y2 = acc[mt][3][j] + bl[3];
        dst[l15]      = f2b((x1*cs0.x - x2*cs0.y)*qs);
        dst[16 + l15] = f2b((y1*cs1.x - y2*cs1.y)*qs);
        dst[32 + l15] = f2b((x2*cs0.x + x1*cs0.y)*qs);
        dst[48 + l15] = f2b((y2*cs1.x + y1*cs1.y)*qs);
      }
  }
}

// -------- per-tile softmax + PV update (R3-exact math; S^T orientation) --------
__device__ __forceinline__ void smax_pv(
    const fx4* s, bool diag, int wl, int q4,
    float& m_run, float& l_run, fx4* o, const f16x4 vf[4][4])
{
  float tv[16];
#pragma unroll
  for (int tl = 0; tl < 4; tl++)
#pragma unroll
    for (int j = 0; j < 4; j++){
      float x = s[tl][j];
      if (diag && (tl*16 + q4*4 + j > wl)) x = -1e30f;
      tv[tl*4+j] = x;
    }
  float mx = tv[0];
#pragma unroll
  for (int i = 1; i < 16; i++) mx = fmaxf(mx, tv[i]);
  mx = fmaxf(mx, __shfl_xor(mx, 16));
  mx = fmaxf(mx, __shfl_xor(mx, 32));
  float mn = fmaxf(m_run, mx);
  float al = exp2f(m_run - mn);
  m_run = mn;
  float p[16], rs = 0.f;
#pragma unroll
  for (int i = 0; i < 16; i++){ p[i] = exp2f(tv[i] - mn); rs += p[i]; }
  rs += __shfl_xor(rs, 16);
  rs += __shfl_xor(rs, 32);
  l_run = l_run*al + rs;
#pragma unroll
  for (int nt = 0; nt < 4; nt++)
#pragma unroll
    for (int j = 0; j < 4; j++) o[nt][j] *= al;
  f16x4 pf[4];
#pragma unroll
  for (int tl = 0; tl < 4; tl++){
    union { f16x4 v; fp16x2 h[2]; } u;
    u.h[0] = __builtin_amdgcn_cvt_pkrtz(p[tl*4+0], p[tl*4+1]);
    u.h[1] = __builtin_amdgcn_cvt_pkrtz(p[tl*4+2], p[tl*4+3]);
    pf[tl] = u.v;
  }
#pragma unroll
  for (int nt = 0; nt < 4; nt++)
#pragma unroll
    for (int tl = 0; tl < 4; tl++)
      o[nt] = __builtin_amdgcn_mfma_f32_16x16x16f16(vf[nt][tl], pf[tl], o[nt], 0,0,0);
}

// ---------------- flash attention: R5 structure + grid split-K (2 halves of the kt range) ----------------
// Grid (32, NH, BT) = 896 blocks: pairx = x&15 selects the (tlo,thi) strip pair, half = x>>4 selects
// the si sub-range. Main loop identical to R5 (dbuf LDS, one barrier/iter, issue-early/write-late).
// Epilogue: in-block g-merge (unchanged) then f32 partial {o,m,l} write; attn_reduce merges halves.
__global__ __launch_bounds__(512) void attn_kernel(
    const unsigned short* __restrict__ q, const unsigned short* __restrict__ k,
    const unsigned short* __restrict__ vt, float* __restrict__ part)
{
  __shared__ short SB[8*64*72];   // 73.7 KB: 2 bufs x {2 K-tiles + 2 V-tiles}; combine F aliases low part

  const int tid = threadIdx.x;
  const int w = tid >> 6, l = tid & 63, l15 = l & 15, q4 = l >> 4;
  const int g = w >> 2, wi = w & 3;
  const int pairx = blockIdx.x & 15, half = blockIdx.x >> 4;
  const int tlo = pairx, thi = 31 - tlo;
  const int h = blockIdx.y, b = blockIdx.z, kvh = h / NREP;
  const int wl = wi*16 + l15;

  const int P  = (thi + 2) >> 1;          // total si count for this pair
  const int Ph = (P + 1) >> 1;            // half 0 size
  const int s0 = half ? Ph : 0;
  const int s1 = half ? P  : Ph;

  const unsigned short* qbase = q + ((size_t)(b*NH + h)*SEQ)*64;
  const unsigned short* qpA = qbase + (size_t)(thi*64 + wl)*64;
  const unsigned short* qpB = qbase + (size_t)(tlo*64 + wl)*64;
  bf16x8 qA0 = *(const bf16x8*)(qpA + q4*8), qA1 = *(const bf16x8*)(qpA + 32 + q4*8);
  bf16x8 qB0 = *(const bf16x8*)(qpB + q4*8), qB1 = *(const bf16x8*)(qpB + 32 + q4*8);

  fx4 oA[4] = {}, oB[4] = {};
  float mA = -1e30f, lA = 0.f, mB = -1e30f, lB = 0.f;

  const unsigned short* kbase = k  + ((size_t)(b*NKV + kvh)*SEQ)*64;
  const unsigned short* vbase = vt + (size_t)((b*NKV + kvh)*(SEQ/64))*4096;

  u16x8 kreg[2], vreg[2];
#pragma unroll
  for (int p2 = 0; p2 < 2; p2++){
    int idx = p2*512 + tid, tile = idx >> 9, off = idx & 511;
    int tk = 2*s0 + tile; if (tk > thi) tk = thi;
    kreg[p2] = *(const u16x8*)(kbase + (size_t)tk*4096 + off*8);
    vreg[p2] = *(const u16x8*)(vbase + (size_t)tk*4096 + off*8);
  }
  {
    const int buf0 = s0 & 1;
#pragma unroll
    for (int p2 = 0; p2 < 2; p2++){
      int idx = p2*512 + tid, tile = idx >> 9, off = idx & 511;
      int rr = off >> 3, g8 = off & 7;
      *(u16x8*)&SB[buf0*18432 + tile*4608 + rr*72 + g8*8] = kreg[p2];
      *(u16x8*)&SB[buf0*18432 + 9216 + tile*4608 + rr*72 + g8*8] = vreg[p2];
    }
  }

  for (int si = s0; si < s1; si++){
    asm volatile("s_waitcnt lgkmcnt(0)\n\ts_barrier" ::: "memory");
    const int p = si & 1;
    const bool more = (si + 1 < s1);

    if (more){
      const int k0n = 2*(si+1);
#pragma unroll
      for (int p2 = 0; p2 < 2; p2++){
        int idx = p2*512 + tid, tile = idx >> 9, off = idx & 511;
        int tk = k0n + tile; if (tk > thi) tk = thi;
        kreg[p2] = *(const u16x8*)(kbase + (size_t)tk*4096 + off*8);
        vreg[p2] = *(const u16x8*)(vbase + (size_t)tk*4096 + off*8);
      }
    }

    const int kt = 2*si + g;
    if (kt <= thi){
      const short* Kst = SB + p*18432 + g*4608;
      const short* Vtt = SB + p*18432 + 9216 + g*4608;
      bf16x8 kf0[4], kf1[4];
#pragma unroll
      for (int tl = 0; tl < 4; tl++){
        kf0[tl] = *(const bf16x8*)&Kst[(tl*16 + l15)*72 + q4*8];
        kf1[tl] = *(const bf16x8*)&Kst[(tl*16 + l15)*72 + 32 + q4*8];
      }
      f16x4 vf[4][4];
#pragma unroll
      for (int nt = 0; nt < 4; nt++)
#pragma unroll
        for (int tl = 0; tl < 4; tl++)
          vf[nt][tl] = *(const f16x4*)&Vtt[(nt*16 + l15)*72 + tl*16 + q4*4];

      {
        fx4 s[4] = {};
#pragma unroll
        for (int tl = 0; tl < 4; tl++){
          s[tl] = __builtin_amdgcn_mfma_f32_16x16x32_bf16(kf0[tl], qA0, s[tl], 0,0,0);
          s[tl] = __builtin_amdgcn_mfma_f32_16x16x32_bf16(kf1[tl], qA1, s[tl], 0,0,0);
        }
        smax_pv(s, kt == thi, wl, q4, mA, lA, oA, vf);
      }
      if (kt <= tlo){
        fx4 s[4] = {};
#pragma unroll
        for (int tl = 0; tl < 4; tl++){
          s[tl] = __builtin_amdgcn_mfma_f32_16x16x32_bf16(kf0[tl], qB0, s[tl], 0,0,0);
          s[tl] = __builtin_amdgcn_mfma_f32_16x16x32_bf16(kf1[tl], qB1, s[tl], 0,0,0);
        }
        smax_pv(s, kt == tlo, wl, q4, mB, lB, oB, vf);
      }
    }

    if (more){
      const int pn = (si & 1) ^ 1;
#pragma unroll
      for (int p2 = 0; p2 < 2; p2++){
        int idx = p2*512 + tid, tile = idx >> 9, off = idx & 511;
        int rr = off >> 3, g8 = off & 7;
        *(u16x8*)&SB[pn*18432 + tile*4608 + rr*72 + g8*8] = kreg[p2];
        *(u16x8*)&SB[pn*18432 + 9216 + tile*4608 + rr*72 + g8*8] = vreg[p2];
      }
    }
  }
  __syncthreads();

  float* F = (float*)SB;
  if (g == 1){
    float* fa = F + (((wi*2 + 0)*64 + l)*18);
#pragma unroll
    for (int nt = 0; nt < 4; nt++)
#pragma unroll
      for (int j = 0; j < 4; j++) fa[nt*4 + j] = oA[nt][j];
    fa[16] = mA; fa[17] = lA;
    float* fb = F + (((wi*2 + 1)*64 + l)*18);
#pragma unroll
    for (int nt = 0; nt < 4; nt++)
#pragma unroll
      for (int j = 0; j < 4; j++) fb[nt*4 + j] = oB[nt][j];
    fb[16] = mB; fb[17] = lB;
  }
  __syncthreads();
  if (g == 0){
    {
      const float* fa = F + (((wi*2 + 0)*64 + l)*18);
      float m1 = fa[16], l1 = fa[17];
      float mM = fmaxf(mA, m1);
      float a0 = exp2f(mA - mM), a1 = exp2f(m1 - mM);
      mA = mM;
      lA = lA*a0 + l1*a1;
#pragma unroll
      for (int nt = 0; nt < 4; nt++)
#pragma unroll
        for (int j = 0; j < 4; j++) oA[nt][j] = oA[nt][j]*a0 + fa[nt*4+j]*a1;
    }
    {
      const float* fb = F + (((wi*2 + 1)*64 + l)*18);
      float m1 = fb[16], l1 = fb[17];
      float mM = fmaxf(mB, m1);
      float a0 = exp2f(mB - mM), a1 = exp2f(m1 - mM);
      mB = mM;
      lB = lB*a0 + l1*a1;
#pragma unroll
      for (int nt = 0; nt < 4; nt++)
#pragma unroll
        for (int j = 0; j < 4; j++) oB[nt][j] = oB[nt][j]*a0 + fb[nt*4+j]*a1;
    }
    // f32 partial write: [half][b][h][pair][strip][row]{o[64], m, l} stride 68 floats
    {
      float* pp = part + ((((((size_t)half*BT + b)*NH + h)*16 + pairx)*2 + 0)*64 + wl)*68;
#pragma unroll
      for (int nt = 0; nt < 4; nt++)
        *(fx4*)(pp + nt*16 + q4*4) = oA[nt];
      if (q4 == 0){ pp[64] = mA; pp[65] = lA; }
    }
    {
      float* pp = part + ((((((size_t)half*BT + b)*NH + h)*16 + pairx)*2 + 1)*64 + wl)*68;
#pragma unroll
      for (int nt = 0; nt < 4; nt++)
        *(fx4*)(pp + nt*16 + q4*4) = oB[nt];
      if (q4 == 0){ pp[64] = mB; pp[65] = lB; }
    }
  }
}

// ---------------- split-K reduce: merge 2 half-partials, normalize, emit bf16 ----------------
__global__ __launch_bounds__(256) void attn_reduce_kernel(
    const float* __restrict__ part, unsigned short* __restrict__ ao)
{
  const int pairx = blockIdx.x, h = blockIdx.y, b = blockIdx.z;
  const int tid = threadIdx.x;
  const int row2 = tid >> 1, hc = tid & 1;
  const int strip = row2 >> 6, row = row2 & 63;
  const int qt = strip ? pairx : (31 - pairx);

  const float* p0 = part + (((((size_t)0*BT + b)*NH + h)*16 + pairx)*2 + strip)*64*68 + (size_t)row*68;
  const float* p1 = part + (((((size_t)1*BT + b)*NH + h)*16 + pairx)*2 + strip)*64*68 + (size_t)row*68;
  float m0 = p0[64], l0 = p0[65], m1 = p1[64], l1 = p1[65];
  float mM = fmaxf(m0, m1);
  float a0 = exp2f(m0 - mM), a1 = exp2f(m1 - mM);
  float inv = 1.0f / (l0*a0 + l1*a1);
  a0 *= inv; a1 *= inv;

  unsigned short* dst = ao + ((size_t)(b*SEQ + qt*64 + row))*HID + h*64 + hc*32;
  const float* q0 = p0 + hc*32;
  const float* q1 = p1 + hc*32;
#pragma unroll
  for (int c = 0; c < 32; c += 4){
    fx4 x0 = *(const fx4*)(q0 + c), x1 = *(const fx4*)(q1 + c);
    s16x4 ov;
    ov[0] = (short)f2b(x0[0]*a0 + x1[0]*a1);
    ov[1] = (short)f2b(x0[1]*a0 + x1[1]*a1);
    ov[2] = (short)f2b(x0[2]*a0 + x1[2]*a1);
    ov[3] = (short)f2b(x0[3]*a0 + x1[3]*a1);
    *(s16x4*)(dst + c) = ov;
  }
}

// ---------------- output projection GEMM: dbuf gll16 pipeline -> fp32 ----------------
__global__ __launch_bounds__(256) void out_gemm_kernel(
    const unsigned short* __restrict__ A, const unsigned short* __restrict__ Bw,
    float* __restrict__ out)
{
  __shared__ short As[2][64*64];
  __shared__ short Bs[2][128*64];
  const int tid = threadIdx.x;
  const int bm = blockIdx.x, bn = blockIdx.y;
  const int w = tid >> 6, l = tid & 63, l15 = l & 15, q4 = l >> 4;
  const int wm = w >> 1, wn = w & 1;
  const int lr = l >> 3;
  const int cbg = (l & 7) ^ lr;
  const int sw = l15 & 7;

  fx4 acc[2][4] = {};

  const unsigned short* Ag = A  + (size_t)(bm*64)*HID;
  const unsigned short* Bg = Bw + (size_t)(bn*128)*HID;

  auto issue = [&](int kt, int buf){
    const int kc = kt*64 + cbg*8;
#pragma unroll
    for (int p = 0; p < 2; p++){
      int c = p*4 + w;
      gll16(Ag + (size_t)(c*8 + lr)*HID + kc, &As[buf][c*512]);
    }
#pragma unroll
    for (int p = 0; p < 4; p++){
      int c = p*4 + w;
      gll16(Bg + (size_t)(c*8 + lr)*HID + kc, &Bs[buf][c*512]);
    }
  };

  issue(0, 0);
  for (int kt = 0; kt < 14; kt++){
    const int cur = kt & 1;
    if (kt < 13){
      issue(kt+1, cur^1);
      asm volatile("s_waitcnt vmcnt(6)\n\ts_barrier" ::: "memory");
    } else {
      asm volatile("s_waitcnt vmcnt(0)\n\ts_barrier" ::: "memory");
    }
#pragma unroll
    for (int ks = 0; ks < 2; ks++){
      bf16x8 af[2], bf[4];
#pragma unroll
      for (int mt = 0; mt < 2; mt++){
        int r = wm*32 + mt*16 + l15;
        af[mt] = *(bf16x8*)&As[cur][r*64 + ((ks*4 + q4) ^ sw)*8];
      }
#pragma unroll
      for (int nt = 0; nt < 4; nt++){
        int r = wn*64 + nt*16 + l15;
        bf[nt] = *(bf16x8*)&Bs[cur][r*64 + ((ks*4 + q4) ^ sw)*8];
      }
#pragma unroll
      for (int mt = 0; mt < 2; mt++)
#pragma unroll
        for (int nt = 0; nt < 4; nt++)
          acc[mt][nt] = __builtin_amdgcn_mfma_f32_16x16x32_bf16(af[mt], bf[nt], acc[mt][nt], 0,0,0);
    }
    asm volatile("s_barrier" ::: "memory");
  }

#pragma unroll
  for (int mt = 0; mt < 2; mt++)
#pragma unroll
    for (int j = 0; j < 4; j++){
      int grow = bm*64 + wm*32 + mt*16 + q4*4 + j;
      float* dst = out + (size_t)grow*HID + bn*128 + wn*64;
#pragma unroll
      for (int nt = 0; nt < 4; nt++)
        dst[nt*16 + l15] = acc[mt][nt][j];
    }
}

extern "C" void kernel_launch(void* const* d_in, const int* in_sizes, int n_in,
                              void* d_out, int out_size, void* d_ws, size_t ws_size,
                              hipStream_t stream)
{
  const float* hidden = (const float*)d_in[0];
  const int*   pos    = (const int*)d_in[1];
  const float* Wq = (const float*)d_in[2]; const float* bq = (const float*)d_in[3];
  const float* Wk = (const float*)d_in[4]; const float* bk = (const float*)d_in[5];
  const float* Wv = (const float*)d_in[6]; const float* bv = (const float*)d_in[7];
  const float* Wo = (const float*)d_in[8];

  unsigned short* qws   = (unsigned short*)d_ws;                       // (B,NH,S,64) bf16 (Q pre-scaled)
  unsigned short* kws   = qws   + (size_t)BT*NH*SEQ*64;                // (B,NKV,S,64) bf16
  unsigned short* vtws  = kws   + (size_t)BT*NKV*SEQ*64;               // (B,NKV,S/64,64,64) f16
  unsigned short* wqkv  = vtws  + (size_t)BT*NKV*SEQ*64;               // (1152,896) bf16
  unsigned short* wo16  = wqkv  + (size_t)1152*HID;                    // (896,896) bf16
  unsigned short* h16   = wo16  + (size_t)HID*HID;                     // (4096,896) bf16: attn-out
  float2*         tab   = (float2*)(h16 + (size_t)NTOK*HID);           // (2048,32) rope table
  float*          part  = (float*)(tab + SEQ*32);                      // split-K partials: 2*2*14*16*2*64*68 f32 (~31 MB)

  const int nwq  = HID*HID;
  const int nwkv = 2*64*HID;

  cvt_kernel<<<dim3(448, 5), 256, 0, stream>>>(
      Wq, Wk, Wv, Wo,
      wqkv, wqkv + nwq, wqkv + nwq + nwkv, wo16,
      nwq, nwkv, nwkv, nwq, tab);

  qkv_gemm_kernel<<<dim3(NTOK/64, 9), 256, 0, stream>>>(
      hidden, wqkv, bq, bk, bv, pos, tab, qws, kws, vtws);

  attn_kernel<<<dim3(32, NH, BT), 512, 0, stream>>>(qws, kws, vtws, part);

  attn_reduce_kernel<<<dim3(16, NH, BT), 256, 0, stream>>>(part, h16);

  out_gemm_kernel<<<dim3(NTOK/64, 7), 256, 0, stream>>>(h16, wo16, (float*)d_out);
}

// Round 7
// 174.676 us; speedup vs baseline: 1.1020x; 1.1020x over previous
//
#include <hip/hip_runtime.h>

#define HID 896
#define NH 14
#define NKV 2
#define NREP 7
#define SEQ 2048
#define BT 2
#define NTOK (BT*SEQ)
#define CSCALE 0.18033688011112042f   // (1/8) * log2(e), folded into Q at projection

typedef __attribute__((ext_vector_type(8))) short bf16x8;
typedef __attribute__((ext_vector_type(8))) unsigned short u16x8;
typedef __attribute__((ext_vector_type(4))) float fx4;
typedef __attribute__((ext_vector_type(4))) short s16x4;
typedef _Float16 f16x4 __attribute__((ext_vector_type(4)));
typedef __fp16 fp16x2 __attribute__((ext_vector_type(2)));

__device__ __forceinline__ unsigned short f2b(float x){
  union { float f; unsigned u; } a; a.f = x;
  unsigned r = a.u + 0x7FFFu + ((a.u >> 16) & 1u);   // RNE
  return (unsigned short)(r >> 16);
}
__device__ __forceinline__ unsigned short f2h(float x){
  union { _Float16 h; unsigned short u; } a; a.h = (_Float16)x; return a.u;
}

// async global->LDS, 16B/lane: LDS dst = wave-uniform base + lane*16 (m97 pattern)
__device__ __forceinline__ void gll16(const unsigned short* g, short* lds){
  __builtin_amdgcn_global_load_lds(
      (const __attribute__((address_space(1))) unsigned int*)(const void*)g,
      (__attribute__((address_space(3))) unsigned int*)(void*)lds, 16, 0, 0);
}

// ------- fp32->bf16 convert (jobs 0..4: hidden + weights) + RoPE table (job 5) -------
__global__ __launch_bounds__(256) void cvt_kernel(
    const float* __restrict__ s0, const float* __restrict__ s1,
    const float* __restrict__ s2, const float* __restrict__ s3,
    const float* __restrict__ s4,
    unsigned short* __restrict__ d0, unsigned short* __restrict__ d1,
    unsigned short* __restrict__ d2, unsigned short* __restrict__ d3,
    unsigned short* __restrict__ d4,
    int c0, int c1, int c2, int c3, int c4,
    float2* __restrict__ tab)
{
  if (blockIdx.y == 5){
    for (int i = blockIdx.x*256 + threadIdx.x; i < SEQ*32; i += gridDim.x*256){
      int s = i >> 5, d = i & 31;
      float f = (float)s * exp2f(-(float)d * 0.62286151779138041f);
      float sv, cv; sincosf(f, &sv, &cv);
      tab[i] = make_float2(cv, sv);
    }
    return;
  }
  const float* s; unsigned short* d; int c;
  switch (blockIdx.y){
    case 0: s=s0; d=d0; c=c0; break;
    case 1: s=s1; d=d1; c=c1; break;
    case 2: s=s2; d=d2; c=c2; break;
    case 3: s=s3; d=d3; c=c3; break;
    default: s=s4; d=d4; c=c4; break;
  }
  for (int i = (blockIdx.x*256 + threadIdx.x)*8; i < c; i += gridDim.x*2048){
    float4 a = *(const float4*)(s + i);
    float4 b = *(const float4*)(s + i + 4);
    u16x8 o;
    o[0]=f2b(a.x); o[1]=f2b(a.y); o[2]=f2b(a.z); o[3]=f2b(a.w);
    o[4]=f2b(b.x); o[5]=f2b(b.y); o[6]=f2b(b.z); o[7]=f2b(b.w);
    *(u16x8*)(d + i) = o;
  }
}

// ---------------- QKV projection GEMM: 128x128 tile (m97 structure), dbuf gll16 ----------------
// A = hidden bf16 [4096,896], B = WQKV bf16 [1152,896]. grid (32,9), block 256 (2x2 waves).
// Per K-step: 32 MFMA vs 8 gll16 (2x the MFMA:staging ratio of the old 64x128 tile).
__global__ __launch_bounds__(256) void qkv_gemm_kernel(
    const unsigned short* __restrict__ A, const unsigned short* __restrict__ Bw,
    const float* __restrict__ bq, const float* __restrict__ bk, const float* __restrict__ bv,
    const int* __restrict__ pos, const float2* __restrict__ tab,
    unsigned short* __restrict__ qo, unsigned short* __restrict__ ko,
    unsigned short* __restrict__ vt)
{
  __shared__ short As[2][128*64];    // 16 KB per buf
  __shared__ short Bs[2][128*64];    // 16 KB per buf  (total 64 KB)
  const int tid = threadIdx.x;
  const int bm = blockIdx.x, bn = blockIdx.y;
  const int w = tid >> 6, l = tid & 63, l15 = l & 15, q4 = l >> 4;
  const int wm = w >> 1, wn = w & 1;
  const int lr = l >> 3;                 // row-in-chunk 0..7
  const int cbg = (l & 7) ^ lr;          // swizzled global 16B-block
  const int sw = l15 & 7;                // frag-read swizzle key

  fx4 acc[4][4] = {};

  const unsigned short* Ag = A  + (size_t)(bm*128)*HID;
  const unsigned short* Bg = Bw + (size_t)(bn*128)*HID;

  auto issue = [&](int kt, int buf){
    const int kc = kt*64 + cbg*8;
#pragma unroll
    for (int p = 0; p < 4; p++){
      int c = p*4 + w;
      gll16(Ag + (size_t)(c*8 + lr)*HID + kc, &As[buf][c*512]);
    }
#pragma unroll
    for (int p = 0; p < 4; p++){
      int c = p*4 + w;
      gll16(Bg + (size_t)(c*8 + lr)*HID + kc, &Bs[buf][c*512]);
    }
  };

  issue(0, 0);
  for (int kt = 0; kt < 14; kt++){
    const int cur = kt & 1;
    if (kt < 13){
      issue(kt+1, cur^1);                                    // 8 more in flight
      asm volatile("s_waitcnt vmcnt(8)\n\ts_barrier" ::: "memory");  // cur landed; next stays out
    } else {
      asm volatile("s_waitcnt vmcnt(0)\n\ts_barrier" ::: "memory");
    }
#pragma unroll
    for (int ks = 0; ks < 2; ks++){
      bf16x8 af[4], bf[4];
#pragma unroll
      for (int mt = 0; mt < 4; mt++){
        int r = wm*64 + mt*16 + l15;
        af[mt] = *(bf16x8*)&As[cur][r*64 + ((ks*4 + q4) ^ sw)*8];
      }
#pragma unroll
      for (int nt = 0; nt < 4; nt++){
        int r = wn*64 + nt*16 + l15;
        bf[nt] = *(bf16x8*)&Bs[cur][r*64 + ((ks*4 + q4) ^ sw)*8];
      }
#pragma unroll
      for (int mt = 0; mt < 4; mt++)
#pragma unroll
        for (int nt = 0; nt < 4; nt++)
          acc[mt][nt] = __builtin_amdgcn_mfma_f32_16x16x32_bf16(af[mt], bf[nt], acc[mt][nt], 0,0,0);
    }
    asm volatile("s_barrier" ::: "memory");                  // buf[cur] free for kt+2 issue
  }

  const int hu = bn*2 + wn;
  const float* bias; int kind, hloc;
  if (hu < NH)      { bias = bq + hu*64;      kind = 0; hloc = hu; }
  else if (hu < 16) { bias = bk + (hu-NH)*64; kind = 1; hloc = hu-NH; }
  else              { bias = bv + (hu-16)*64; kind = 2; hloc = hu-16; }
  float bl[4];
#pragma unroll
  for (int nt = 0; nt < 4; nt++) bl[nt] = bias[nt*16 + l15];

  if (kind == 2){
#pragma unroll
    for (int mt = 0; mt < 4; mt++)
#pragma unroll
      for (int j = 0; j < 4; j++){
        int grow = bm*128 + wm*64 + mt*16 + q4*4 + j;
        int b = grow >> 11, s = grow & (SEQ-1);
        int tile = s >> 6, key = s & 63;
        unsigned short* dst = vt + (size_t)(((b*NKV + hloc)*(SEQ/64) + tile)*4096);
#pragma unroll
        for (int nt = 0; nt < 4; nt++)
          dst[(nt*16 + l15)*64 + key] = f2h(acc[mt][nt][j] + bl[nt]);
      }
  } else {
    const float qs = (kind == 0) ? CSCALE : 1.0f;
#pragma unroll
    for (int mt = 0; mt < 4; mt++)
#pragma unroll
      for (int j = 0; j < 4; j++){
        int grow = bm*128 + wm*64 + mt*16 + q4*4 + j;
        int b = grow >> 11, s = grow & (SEQ-1);
        int p = pos[grow];
        const float2* rp = tab + p*32 + l15;
        float2 cs0 = rp[0], cs1 = rp[16];
        unsigned short* dst = (kind == 0)
            ? qo + ((size_t)(b*NH  + hloc)*SEQ + s)*64
            : ko + ((size_t)(b*NKV + hloc)*SEQ + s)*64;
        float x1 = acc[mt][0][j] + bl[0], x2 = acc[mt][2][j] + bl[2];
        float y1 = acc[mt][1][j] + bl[1], y2 = acc[mt][3][j] + bl[3];
        dst[l15]      = f2b((x1*cs0.x - x2*cs0.y)*qs);
        dst[16 + l15] = f2b((y1*cs1.x - y2*cs1.y)*qs);
        dst[32 + l15] = f2b((x2*cs0.x + x1*cs0.y)*qs);
        dst[48 + l15] = f2b((y2*cs1.x + y1*cs1.y)*qs);
      }
  }
}

// -------- per-tile softmax + PV update (R3-exact math; S^T orientation) --------
__device__ __forceinline__ void smax_pv(
    const fx4* s, bool diag, int wl, int q4,
    float& m_run, float& l_run, fx4* o, const f16x4 vf[4][4])
{
  float tv[16];
#pragma unroll
  for (int tl = 0; tl < 4; tl++)
#pragma unroll
    for (int j = 0; j < 4; j++){
      float x = s[tl][j];
      if (diag && (tl*16 + q4*4 + j > wl)) x = -1e30f;
      tv[tl*4+j] = x;
    }
  float mx = tv[0];
#pragma unroll
  for (int i = 1; i < 16; i++) mx = fmaxf(mx, tv[i]);
  mx = fmaxf(mx, __shfl_xor(mx, 16));
  mx = fmaxf(mx, __shfl_xor(mx, 32));
  float mn = fmaxf(m_run, mx);
  float al = exp2f(m_run - mn);
  m_run = mn;
  float p[16], rs = 0.f;
#pragma unroll
  for (int i = 0; i < 16; i++){ p[i] = exp2f(tv[i] - mn); rs += p[i]; }
  rs += __shfl_xor(rs, 16);
  rs += __shfl_xor(rs, 32);
  l_run = l_run*al + rs;
#pragma unroll
  for (int nt = 0; nt < 4; nt++)
#pragma unroll
    for (int j = 0; j < 4; j++) o[nt][j] *= al;
  f16x4 pf[4];
#pragma unroll
  for (int tl = 0; tl < 4; tl++){
    union { f16x4 v; fp16x2 h[2]; } u;
    u.h[0] = __builtin_amdgcn_cvt_pkrtz(p[tl*4+0], p[tl*4+1]);
    u.h[1] = __builtin_amdgcn_cvt_pkrtz(p[tl*4+2], p[tl*4+3]);
    pf[tl] = u.v;
  }
#pragma unroll
  for (int nt = 0; nt < 4; nt++)
#pragma unroll
    for (int tl = 0; tl < 4; tl++)
      o[nt] = __builtin_amdgcn_mfma_f32_16x16x16f16(vf[nt][tl], pf[tl], o[nt], 0,0,0);
}

// ---------------- flash attention: paired strips + split-K, dbuf LDS, ONE barrier/iter (R5) ----------------
__global__ __launch_bounds__(512) void attn_kernel(
    const unsigned short* __restrict__ q, const unsigned short* __restrict__ k,
    const unsigned short* __restrict__ vt, unsigned short* __restrict__ ao)
{
  __shared__ short SB[8*64*72];   // 73.7 KB: 2 bufs x {2 K-tiles + 2 V-tiles}; combine F aliases low part

  const int tid = threadIdx.x;
  const int w = tid >> 6, l = tid & 63, l15 = l & 15, q4 = l >> 4;
  const int g = w >> 2, wi = w & 3;
  const int tlo = blockIdx.x, thi = 31 - tlo;
  const int h = blockIdx.y, b = blockIdx.z, kvh = h / NREP;
  const int wl = wi*16 + l15;

  const unsigned short* qbase = q + ((size_t)(b*NH + h)*SEQ)*64;
  const unsigned short* qpA = qbase + (size_t)(thi*64 + wl)*64;
  const unsigned short* qpB = qbase + (size_t)(tlo*64 + wl)*64;
  bf16x8 qA0 = *(const bf16x8*)(qpA + q4*8), qA1 = *(const bf16x8*)(qpA + 32 + q4*8);
  bf16x8 qB0 = *(const bf16x8*)(qpB + q4*8), qB1 = *(const bf16x8*)(qpB + 32 + q4*8);

  fx4 oA[4] = {}, oB[4] = {};
  float mA = -1e30f, lA = 0.f, mB = -1e30f, lB = 0.f;

  const unsigned short* kbase = k  + ((size_t)(b*NKV + kvh)*SEQ)*64;
  const unsigned short* vbase = vt + (size_t)((b*NKV + kvh)*(SEQ/64))*4096;

  const int P = (thi + 2) >> 1;

  u16x8 kreg[2], vreg[2];
#pragma unroll
  for (int p2 = 0; p2 < 2; p2++){
    int idx = p2*512 + tid, tile = idx >> 9, off = idx & 511;
    kreg[p2] = *(const u16x8*)(kbase + (size_t)tile*4096 + off*8);
    vreg[p2] = *(const u16x8*)(vbase + (size_t)tile*4096 + off*8);
  }
#pragma unroll
  for (int p2 = 0; p2 < 2; p2++){
    int idx = p2*512 + tid, tile = idx >> 9, off = idx & 511;
    int rr = off >> 3, g8 = off & 7;
    *(u16x8*)&SB[tile*4608 + rr*72 + g8*8] = kreg[p2];
    *(u16x8*)&SB[9216 + tile*4608 + rr*72 + g8*8] = vreg[p2];
  }

  for (int si = 0; si < P; si++){
    asm volatile("s_waitcnt lgkmcnt(0)\n\ts_barrier" ::: "memory");
    const int p = si & 1;
    const bool more = (si + 1 < P);

    if (more){
      const int k0n = 2*(si+1);
#pragma unroll
      for (int p2 = 0; p2 < 2; p2++){
        int idx = p2*512 + tid, tile = idx >> 9, off = idx & 511;
        int tk = k0n + tile; if (tk > thi) tk = thi;
        kreg[p2] = *(const u16x8*)(kbase + (size_t)tk*4096 + off*8);
        vreg[p2] = *(const u16x8*)(vbase + (size_t)tk*4096 + off*8);
      }
    }

    const int kt = 2*si + g;
    if (kt <= thi){
      const short* Kst = SB + p*18432 + g*4608;
      const short* Vtt = SB + p*18432 + 9216 + g*4608;
      bf16x8 kf0[4], kf1[4];
#pragma unroll
      for (int tl = 0; tl < 4; tl++){
        kf0[tl] = *(const bf16x8*)&Kst[(tl*16 + l15)*72 + q4*8];
        kf1[tl] = *(const bf16x8*)&Kst[(tl*16 + l15)*72 + 32 + q4*8];
      }
      f16x4 vf[4][4];
#pragma unroll
      for (int nt = 0; nt < 4; nt++)
#pragma unroll
        for (int tl = 0; tl < 4; tl++)
          vf[nt][tl] = *(const f16x4*)&Vtt[(nt*16 + l15)*72 + tl*16 + q4*4];

      {
        fx4 s[4] = {};
#pragma unroll
        for (int tl = 0; tl < 4; tl++){
          s[tl] = __builtin_amdgcn_mfma_f32_16x16x32_bf16(kf0[tl], qA0, s[tl], 0,0,0);
          s[tl] = __builtin_amdgcn_mfma_f32_16x16x32_bf16(kf1[tl], qA1, s[tl], 0,0,0);
        }
        smax_pv(s, kt == thi, wl, q4, mA, lA, oA, vf);
      }
      if (kt <= tlo){
        fx4 s[4] = {};
#pragma unroll
        for (int tl = 0; tl < 4; tl++){
          s[tl] = __builtin_amdgcn_mfma_f32_16x16x32_bf16(kf0[tl], qB0, s[tl], 0,0,0);
          s[tl] = __builtin_amdgcn_mfma_f32_16x16x32_bf16(kf1[tl], qB1, s[tl], 0,0,0);
        }
        smax_pv(s, kt == tlo, wl, q4, mB, lB, oB, vf);
      }
    }

    if (more){
      const int pn = (si & 1) ^ 1;
#pragma unroll
      for (int p2 = 0; p2 < 2; p2++){
        int idx = p2*512 + tid, tile = idx >> 9, off = idx & 511;
        int rr = off >> 3, g8 = off & 7;
        *(u16x8*)&SB[pn*18432 + tile*4608 + rr*72 + g8*8] = kreg[p2];
        *(u16x8*)&SB[pn*18432 + 9216 + tile*4608 + rr*72 + g8*8] = vreg[p2];
      }
    }
  }
  __syncthreads();

  float* F = (float*)SB;
  if (g == 1){
    float* fa = F + (((wi*2 + 0)*64 + l)*18);
#pragma unroll
    for (int nt = 0; nt < 4; nt++)
#pragma unroll
      for (int j = 0; j < 4; j++) fa[nt*4 + j] = oA[nt][j];
    fa[16] = mA; fa[17] = lA;
    float* fb = F + (((wi*2 + 1)*64 + l)*18);
#pragma unroll
    for (int nt = 0; nt < 4; nt++)
#pragma unroll
      for (int j = 0; j < 4; j++) fb[nt*4 + j] = oB[nt][j];
    fb[16] = mB; fb[17] = lB;
  }
  __syncthreads();
  if (g == 0){
    {
      const float* fa = F + (((wi*2 + 0)*64 + l)*18);
      float m1 = fa[16], l1 = fa[17];
      float mM = fmaxf(mA, m1);
      float a0 = exp2f(mA - mM), a1 = exp2f(m1 - mM);
      lA = lA*a0 + l1*a1;
#pragma unroll
      for (int nt = 0; nt < 4; nt++)
#pragma unroll
        for (int j = 0; j < 4; j++) oA[nt][j] = oA[nt][j]*a0 + fa[nt*4+j]*a1;
    }
    {
      const float* fb = F + (((wi*2 + 1)*64 + l)*18);
      float m1 = fb[16], l1 = fb[17];
      float mM = fmaxf(mB, m1);
      float a0 = exp2f(mB - mM), a1 = exp2f(m1 - mM);
      lB = lB*a0 + l1*a1;
#pragma unroll
      for (int nt = 0; nt < 4; nt++)
#pragma unroll
        for (int j = 0; j < 4; j++) oB[nt][j] = oB[nt][j]*a0 + fb[nt*4+j]*a1;
    }
    {
      float inv = 1.0f / lA;
      unsigned short* dst = ao + ((size_t)(b*SEQ + thi*64 + wl))*HID + h*64;
#pragma unroll
      for (int nt = 0; nt < 4; nt++){
        s16x4 ov;
        ov[0] = (short)f2b(oA[nt][0]*inv); ov[1] = (short)f2b(oA[nt][1]*inv);
        ov[2] = (short)f2b(oA[nt][2]*inv); ov[3] = (short)f2b(oA[nt][3]*inv);
        *(s16x4*)(dst + nt*16 + q4*4) = ov;
      }
    }
    {
      float inv = 1.0f / lB;
      unsigned short* dst = ao + ((size_t)(b*SEQ + tlo*64 + wl))*HID + h*64;
#pragma unroll
      for (int nt = 0; nt < 4; nt++){
        s16x4 ov;
        ov[0] = (short)f2b(oB[nt][0]*inv); ov[1] = (short)f2b(oB[nt][1]*inv);
        ov[2] = (short)f2b(oB[nt][2]*inv); ov[3] = (short)f2b(oB[nt][3]*inv);
        *(s16x4*)(dst + nt*16 + q4*4) = ov;
      }
    }
  }
}

// ---------------- output projection GEMM: 128x128 tile (m97 structure), dbuf gll16 -> fp32 ----------------
// A = attn bf16 [4096,896], B = Wo bf16 [896,896]. grid (32, 7), block 256.
__global__ __launch_bounds__(256) void out_gemm_kernel(
    const unsigned short* __restrict__ A, const unsigned short* __restrict__ Bw,
    float* __restrict__ out)
{
  __shared__ short As[2][128*64];
  __shared__ short Bs[2][128*64];
  const int tid = threadIdx.x;
  const int bm = blockIdx.x, bn = blockIdx.y;
  const int w = tid >> 6, l = tid & 63, l15 = l & 15, q4 = l >> 4;
  const int wm = w >> 1, wn = w & 1;
  const int lr = l >> 3;
  const int cbg = (l & 7) ^ lr;
  const int sw = l15 & 7;

  fx4 acc[4][4] = {};

  const unsigned short* Ag = A  + (size_t)(bm*128)*HID;
  const unsigned short* Bg = Bw + (size_t)(bn*128)*HID;

  auto issue = [&](int kt, int buf){
    const int kc = kt*64 + cbg*8;
#pragma unroll
    for (int p = 0; p < 4; p++){
      int c = p*4 + w;
      gll16(Ag + (size_t)(c*8 + lr)*HID + kc, &As[buf][c*512]);
    }
#pragma unroll
    for (int p = 0; p < 4; p++){
      int c = p*4 + w;
      gll16(Bg + (size_t)(c*8 + lr)*HID + kc, &Bs[buf][c*512]);
    }
  };

  issue(0, 0);
  for (int kt = 0; kt < 14; kt++){
    const int cur = kt & 1;
    if (kt < 13){
      issue(kt+1, cur^1);
      asm volatile("s_waitcnt vmcnt(8)\n\ts_barrier" ::: "memory");
    } else {
      asm volatile("s_waitcnt vmcnt(0)\n\ts_barrier" ::: "memory");
    }
#pragma unroll
    for (int ks = 0; ks < 2; ks++){
      bf16x8 af[4], bf[4];
#pragma unroll
      for (int mt = 0; mt < 4; mt++){
        int r = wm*64 + mt*16 + l15;
        af[mt] = *(bf16x8*)&As[cur][r*64 + ((ks*4 + q4) ^ sw)*8];
      }
#pragma unroll
      for (int nt = 0; nt < 4; nt++){
        int r = wn*64 + nt*16 + l15;
        bf[nt] = *(bf16x8*)&Bs[cur][r*64 + ((ks*4 + q4) ^ sw)*8];
      }
#pragma unroll
      for (int mt = 0; mt < 4; mt++)
#pragma unroll
        for (int nt = 0; nt < 4; nt++)
          acc[mt][nt] = __builtin_amdgcn_mfma_f32_16x16x32_bf16(af[mt], bf[nt], acc[mt][nt], 0,0,0);
    }
    asm volatile("s_barrier" ::: "memory");
  }

#pragma unroll
  for (int mt = 0; mt < 4; mt++)
#pragma unroll
    for (int j = 0; j < 4; j++){
      int grow = bm*128 + wm*64 + mt*16 + q4*4 + j;
      float* dst = out + (size_t)grow*HID + bn*128 + wn*64;
#pragma unroll
      for (int nt = 0; nt < 4; nt++)
        dst[nt*16 + l15] = acc[mt][nt][j];
    }
}

extern "C" void kernel_launch(void* const* d_in, const int* in_sizes, int n_in,
                              void* d_out, int out_size, void* d_ws, size_t ws_size,
                              hipStream_t stream)
{
  const float* hidden = (const float*)d_in[0];
  const int*   pos    = (const int*)d_in[1];
  const float* Wq = (const float*)d_in[2]; const float* bq = (const float*)d_in[3];
  const float* Wk = (const float*)d_in[4]; const float* bk = (const float*)d_in[5];
  const float* Wv = (const float*)d_in[6]; const float* bv = (const float*)d_in[7];
  const float* Wo = (const float*)d_in[8];

  unsigned short* qws   = (unsigned short*)d_ws;                       // (B,NH,S,64) bf16 (Q pre-scaled)
  unsigned short* kws   = qws   + (size_t)BT*NH*SEQ*64;                // (B,NKV,S,64) bf16
  unsigned short* vtws  = kws   + (size_t)BT*NKV*SEQ*64;               // (B,NKV,S/64,64,64) f16
  unsigned short* wqkv  = vtws  + (size_t)BT*NKV*SEQ*64;               // (1152,896) bf16
  unsigned short* wo16  = wqkv  + (size_t)1152*HID;                    // (896,896) bf16
  unsigned short* h16   = wo16  + (size_t)HID*HID;                     // (4096,896) bf16: hidden, then attn-out
  float2*         tab   = (float2*)(h16 + (size_t)NTOK*HID);           // (2048,32) rope table

  const int nh   = NTOK*HID;
  const int nwq  = HID*HID;
  const int nwkv = 2*64*HID;

  cvt_kernel<<<dim3(448, 6), 256, 0, stream>>>(
      hidden, Wq, Wk, Wv, Wo,
      h16, wqkv, wqkv + nwq, wqkv + nwq + nwkv, wo16,
      nh, nwq, nwkv, nwkv, nwq, tab);

  qkv_gemm_kernel<<<dim3(NTOK/128, 9), 256, 0, stream>>>(
      h16, wqkv, bq, bk, bv, pos, tab, qws, kws, vtws);

  attn_kernel<<<dim3(16, NH, BT), 512, 0, stream>>>(qws, kws, vtws, h16);

  out_gemm_kernel<<<dim3(NTOK/128, 7), 256, 0, stream>>>(h16, wo16, (float*)d_out);
}

// Round 8
// 167.316 us; speedup vs baseline: 1.1504x; 1.0440x over previous
//
#include <hip/hip_runtime.h>

#define HID 896
#define NH 14
#define NKV 2
#define NREP 7
#define SEQ 2048
#define BT 2
#define NTOK (BT*SEQ)
#define CSCALE 0.18033688011112042f   // (1/8) * log2(e), folded into Q at projection

typedef __attribute__((ext_vector_type(8))) short bf16x8;
typedef __attribute__((ext_vector_type(8))) unsigned short u16x8;
typedef __attribute__((ext_vector_type(4))) float fx4;
typedef __attribute__((ext_vector_type(4))) short s16x4;
typedef _Float16 f16x4 __attribute__((ext_vector_type(4)));
typedef __fp16 fp16x2 __attribute__((ext_vector_type(2)));

__device__ __forceinline__ unsigned short f2b(float x){
  union { float f; unsigned u; } a; a.f = x;
  unsigned r = a.u + 0x7FFFu + ((a.u >> 16) & 1u);   // RNE
  return (unsigned short)(r >> 16);
}
__device__ __forceinline__ unsigned short f2h(float x){
  union { _Float16 h; unsigned short u; } a; a.h = (_Float16)x; return a.u;
}

// async global->LDS, 16B/lane: LDS dst = wave-uniform base + lane*16 (m97 pattern)
__device__ __forceinline__ void gll16(const unsigned short* g, short* lds){
  __builtin_amdgcn_global_load_lds(
      (const __attribute__((address_space(1))) unsigned int*)(const void*)g,
      (__attribute__((address_space(3))) unsigned int*)(void*)lds, 16, 0, 0);
}

// ------- fp32->bf16 convert (weights only; hidden is folded into qkv A-staging) -------
__global__ __launch_bounds__(256) void cvt_kernel(
    const float* __restrict__ s0, const float* __restrict__ s1,
    const float* __restrict__ s2, const float* __restrict__ s3,
    unsigned short* __restrict__ d0, unsigned short* __restrict__ d1,
    unsigned short* __restrict__ d2, unsigned short* __restrict__ d3,
    int c0, int c1, int c2, int c3,
    float2* __restrict__ tab)
{
  if (blockIdx.y == 4){
    for (int i = blockIdx.x*256 + threadIdx.x; i < SEQ*32; i += gridDim.x*256){
      int s = i >> 5, d = i & 31;
      float f = (float)s * exp2f(-(float)d * 0.62286151779138041f);
      float sv, cv; sincosf(f, &sv, &cv);
      tab[i] = make_float2(cv, sv);
    }
    return;
  }
  const float* s; unsigned short* d; int c;
  switch (blockIdx.y){
    case 0: s=s0; d=d0; c=c0; break;
    case 1: s=s1; d=d1; c=c1; break;
    case 2: s=s2; d=d2; c=c2; break;
    default: s=s3; d=d3; c=c3; break;
  }
  for (int i = (blockIdx.x*256 + threadIdx.x)*8; i < c; i += gridDim.x*2048){
    float4 a = *(const float4*)(s + i);
    float4 b = *(const float4*)(s + i + 4);
    u16x8 o;
    o[0]=f2b(a.x); o[1]=f2b(a.y); o[2]=f2b(a.z); o[3]=f2b(a.w);
    o[4]=f2b(b.x); o[5]=f2b(b.y); o[6]=f2b(b.z); o[7]=f2b(b.w);
    *(u16x8*)(d + i) = o;
  }
}

// ---------------- QKV projection GEMM: A from fp32 hidden (reg-staged cvt), B via gll16 ----------------
// A = hidden fp32 [4096,896] (converted in-register to bf16, ds_write to same swizzled layout),
// B = WQKV bf16 [1152,896]. grid (64,9), block 256 (2x2 waves).
// Areg consumption forces the implicit vmcnt drain (covers older B gll16 too); lgkmcnt(0)+barrier
// publishes the A ds_writes; B gll16(kt+1) + A loads(kt+1) stay in flight across compute(kt).
__global__ __launch_bounds__(256) void qkv_gemm_kernel(
    const float* __restrict__ Ahid, const unsigned short* __restrict__ Bw,
    const float* __restrict__ bq, const float* __restrict__ bk, const float* __restrict__ bv,
    const int* __restrict__ pos, const float2* __restrict__ tab,
    unsigned short* __restrict__ qo, unsigned short* __restrict__ ko,
    unsigned short* __restrict__ vt)
{
  __shared__ short As[2][64*64];     // 16 KB
  __shared__ short Bs[2][128*64];    // 32 KB
  const int tid = threadIdx.x;
  const int bm = blockIdx.x, bn = blockIdx.y;
  const int w = tid >> 6, l = tid & 63, l15 = l & 15, q4 = l >> 4;
  const int wm = w >> 1, wn = w & 1;
  const int lr = l >> 3;                 // row-in-chunk 0..7
  const int cbg = (l & 7) ^ lr;          // swizzled global 16B-block
  const int sw = l15 & 7;                // frag-read swizzle key

  fx4 acc[2][4] = {};

  const float*          Ag = Ahid + (size_t)(bm*64)*HID;
  const unsigned short* Bg = Bw   + (size_t)(bn*128)*HID;

  float4 Areg[2][2];
  auto loadA = [&](int kt){
    const int kc = kt*64 + cbg*8;
#pragma unroll
    for (int p = 0; p < 2; p++){
      const float* src = Ag + (size_t)((p*4 + w)*8 + lr)*HID + kc;
      Areg[p][0] = *(const float4*)(src);
      Areg[p][1] = *(const float4*)(src + 4);
    }
  };
  auto storeA = [&](int buf){
#pragma unroll
    for (int p = 0; p < 2; p++){
      int c = p*4 + w;
      u16x8 o;
      o[0]=f2b(Areg[p][0].x); o[1]=f2b(Areg[p][0].y);
      o[2]=f2b(Areg[p][0].z); o[3]=f2b(Areg[p][0].w);
      o[4]=f2b(Areg[p][1].x); o[5]=f2b(Areg[p][1].y);
      o[6]=f2b(Areg[p][1].z); o[7]=f2b(Areg[p][1].w);
      *(u16x8*)&As[buf][c*512 + l*8] = o;
    }
  };
  auto issueB = [&](int kt, int buf){
    const int kc = kt*64 + cbg*8;
#pragma unroll
    for (int p = 0; p < 4; p++){
      int c = p*4 + w;
      gll16(Bg + (size_t)(c*8 + lr)*HID + kc, &Bs[buf][c*512]);
    }
  };

  issueB(0, 0);
  loadA(0);
  for (int kt = 0; kt < 14; kt++){
    const int cur = kt & 1;
    storeA(cur);                         // implicit vmcnt drain: A(kt) + older B(kt) landed
    if (kt < 13){
      issueB(kt+1, cur^1);
      loadA(kt+1);                       // in flight across this iter's compute
    }
    asm volatile("s_waitcnt lgkmcnt(0)\n\ts_barrier" ::: "memory");
#pragma unroll
    for (int ks = 0; ks < 2; ks++){
      bf16x8 af[2], bf[4];
#pragma unroll
      for (int mt = 0; mt < 2; mt++){
        int r = wm*32 + mt*16 + l15;
        af[mt] = *(bf16x8*)&As[cur][r*64 + ((ks*4 + q4) ^ sw)*8];
      }
#pragma unroll
      for (int nt = 0; nt < 4; nt++){
        int r = wn*64 + nt*16 + l15;
        bf[nt] = *(bf16x8*)&Bs[cur][r*64 + ((ks*4 + q4) ^ sw)*8];
      }
#pragma unroll
      for (int mt = 0; mt < 2; mt++)
#pragma unroll
        for (int nt = 0; nt < 4; nt++)
          acc[mt][nt] = __builtin_amdgcn_mfma_f32_16x16x32_bf16(af[mt], bf[nt], acc[mt][nt], 0,0,0);
    }
    asm volatile("s_barrier" ::: "memory");                  // buf[cur] free for kt+2 staging
  }

  const int hu = bn*2 + wn;
  const float* bias; int kind, hloc;
  if (hu < NH)      { bias = bq + hu*64;      kind = 0; hloc = hu; }
  else if (hu < 16) { bias = bk + (hu-NH)*64; kind = 1; hloc = hu-NH; }
  else              { bias = bv + (hu-16)*64; kind = 2; hloc = hu-16; }
  float bl[4];
#pragma unroll
  for (int nt = 0; nt < 4; nt++) bl[nt] = bias[nt*16 + l15];

  if (kind == 2){
#pragma unroll
    for (int mt = 0; mt < 2; mt++)
#pragma unroll
      for (int j = 0; j < 4; j++){
        int grow = bm*64 + wm*32 + mt*16 + q4*4 + j;
        int b = grow >> 11, s = grow & (SEQ-1);
        int tile = s >> 6, key = s & 63;
        unsigned short* dst = vt + (size_t)(((b*NKV + hloc)*(SEQ/64) + tile)*4096);
#pragma unroll
        for (int nt = 0; nt < 4; nt++)
          dst[(nt*16 + l15)*64 + key] = f2h(acc[mt][nt][j] + bl[nt]);
      }
  } else {
    const float qs = (kind == 0) ? CSCALE : 1.0f;
#pragma unroll
    for (int mt = 0; mt < 2; mt++)
#pragma unroll
      for (int j = 0; j < 4; j++){
        int grow = bm*64 + wm*32 + mt*16 + q4*4 + j;
        int b = grow >> 11, s = grow & (SEQ-1);
        int p = pos[grow];
        const float2* rp = tab + p*32 + l15;
        float2 cs0 = rp[0], cs1 = rp[16];
        unsigned short* dst = (kind == 0)
            ? qo + ((size_t)(b*NH  + hloc)*SEQ + s)*64
            : ko + ((size_t)(b*NKV + hloc)*SEQ + s)*64;
        float x1 = acc[mt][0][j] + bl[0], x2 = acc[mt][2][j] + bl[2];
        float y1 = acc[mt][1][j] + bl[1], y2 = acc[mt][3][j] + bl[3];
        dst[l15]      = f2b((x1*cs0.x - x2*cs0.y)*qs);
        dst[16 + l15] = f2b((y1*cs1.x - y2*cs1.y)*qs);
        dst[32 + l15] = f2b((x2*cs0.x + x1*cs0.y)*qs);
        dst[48 + l15] = f2b((y2*cs1.x + y1*cs1.y)*qs);
      }
  }
}

// -------- per-tile softmax + PV update (S^T orientation; CSCALE pre-folded into Q) --------
__device__ __forceinline__ void smax_pv(
    const fx4* s, bool diag, int wl, int q4,
    float& m_run, float& l_run, fx4* o, const f16x4 vf[4][4])
{
  float tv[16];
#pragma unroll
  for (int tl = 0; tl < 4; tl++)
#pragma unroll
    for (int j = 0; j < 4; j++){
      float x = s[tl][j];
      if (diag && (tl*16 + q4*4 + j > wl)) x = -1e30f;
      tv[tl*4+j] = x;
    }
  float mx = tv[0];
#pragma unroll
  for (int i = 1; i < 16; i++) mx = fmaxf(mx, tv[i]);
  mx = fmaxf(mx, __shfl_xor(mx, 16));
  mx = fmaxf(mx, __shfl_xor(mx, 32));
  float mn = fmaxf(m_run, mx);
  float al = exp2f(m_run - mn);
  m_run = mn;
  float p[16], rs = 0.f;
#pragma unroll
  for (int i = 0; i < 16; i++){ p[i] = exp2f(tv[i] - mn); rs += p[i]; }
  rs += __shfl_xor(rs, 16);
  rs += __shfl_xor(rs, 32);
  l_run = l_run*al + rs;
#pragma unroll
  for (int nt = 0; nt < 4; nt++)
#pragma unroll
    for (int j = 0; j < 4; j++) o[nt][j] *= al;
  f16x4 pf[4];
#pragma unroll
  for (int tl = 0; tl < 4; tl++){
    union { f16x4 v; fp16x2 h[2]; } u;
    u.h[0] = __builtin_amdgcn_cvt_pkrtz(p[tl*4+0], p[tl*4+1]);
    u.h[1] = __builtin_amdgcn_cvt_pkrtz(p[tl*4+2], p[tl*4+3]);
    pf[tl] = u.v;
  }
#pragma unroll
  for (int nt = 0; nt < 4; nt++)
#pragma unroll
    for (int tl = 0; tl < 4; tl++)
      o[nt] = __builtin_amdgcn_mfma_f32_16x16x16f16(vf[nt][tl], pf[tl], o[nt], 0,0,0);
}

// ---------------- flash attention (paired strips + split-K; best measured 57.9us) ----------------
__global__ __launch_bounds__(512) void attn_kernel(
    const unsigned short* __restrict__ q, const unsigned short* __restrict__ k,
    const unsigned short* __restrict__ vt, unsigned short* __restrict__ ao)
{
  __shared__ short SB[4*64*72];
  short* KsB = SB;
  short* VtB = SB + 2*64*72;

  const int tid = threadIdx.x;
  const int w = tid >> 6, l = tid & 63, l15 = l & 15, q4 = l >> 4;
  const int g = w >> 2, wi = w & 3;
  const int tlo = blockIdx.x, thi = 31 - tlo;
  const int h = blockIdx.y, b = blockIdx.z, kvh = h / NREP;
  const int wl = wi*16 + l15;

  const unsigned short* qbase = q + ((size_t)(b*NH + h)*SEQ)*64;
  const unsigned short* qpA = qbase + (size_t)(thi*64 + wl)*64;
  const unsigned short* qpB = qbase + (size_t)(tlo*64 + wl)*64;
  bf16x8 qA0 = *(const bf16x8*)(qpA + q4*8), qA1 = *(const bf16x8*)(qpA + 32 + q4*8);
  bf16x8 qB0 = *(const bf16x8*)(qpB + q4*8), qB1 = *(const bf16x8*)(qpB + 32 + q4*8);

  fx4 oA[4] = {}, oB[4] = {};
  float mA = -1e30f, lA = 0.f, mB = -1e30f, lB = 0.f;

  const unsigned short* kbase = k  + ((size_t)(b*NKV + kvh)*SEQ)*64;
  const unsigned short* vbase = vt + (size_t)((b*NKV + kvh)*(SEQ/64))*4096;

  const int P = (thi + 2) >> 1;

  u16x8 kreg[2], vreg[2];
#pragma unroll
  for (int p = 0; p < 2; p++){
    int idx = p*512 + tid, tile = idx >> 9, off = idx & 511;
    kreg[p] = *(const u16x8*)(kbase + (size_t)tile*4096 + off*8);
    vreg[p] = *(const u16x8*)(vbase + (size_t)tile*4096 + off*8);
  }

  for (int si = 0; si < P; si++){
#pragma unroll
    for (int p = 0; p < 2; p++){
      int idx = p*512 + tid, tile = idx >> 9, off = idx & 511;
      int rr = off >> 3, g8 = off & 7;
      *(u16x8*)&KsB[tile*4608 + rr*72 + g8*8] = kreg[p];
      *(u16x8*)&VtB[tile*4608 + rr*72 + g8*8] = vreg[p];
    }
    __syncthreads();

    if (si + 1 < P){
      const int k0n = 2*(si+1);
#pragma unroll
      for (int p = 0; p < 2; p++){
        int idx = p*512 + tid, tile = idx >> 9, off = idx & 511;
        int tk = k0n + tile; if (tk > thi) tk = thi;
        kreg[p] = *(const u16x8*)(kbase + (size_t)tk*4096 + off*8);
        vreg[p] = *(const u16x8*)(vbase + (size_t)tk*4096 + off*8);
      }
    }

    const int kt = 2*si + g;
    if (kt <= thi){
      const short* Kst = KsB + g*4608;
      const short* Vtt = VtB + g*4608;
      bf16x8 kf0[4], kf1[4];
#pragma unroll
      for (int tl = 0; tl < 4; tl++){
        kf0[tl] = *(const bf16x8*)&Kst[(tl*16 + l15)*72 + q4*8];
        kf1[tl] = *(const bf16x8*)&Kst[(tl*16 + l15)*72 + 32 + q4*8];
      }
      f16x4 vf[4][4];
#pragma unroll
      for (int nt = 0; nt < 4; nt++)
#pragma unroll
        for (int tl = 0; tl < 4; tl++)
          vf[nt][tl] = *(const f16x4*)&Vtt[(nt*16 + l15)*72 + tl*16 + q4*4];

      {
        fx4 s[4] = {};
#pragma unroll
        for (int tl = 0; tl < 4; tl++){
          s[tl] = __builtin_amdgcn_mfma_f32_16x16x32_bf16(kf0[tl], qA0, s[tl], 0,0,0);
          s[tl] = __builtin_amdgcn_mfma_f32_16x16x32_bf16(kf1[tl], qA1, s[tl], 0,0,0);
        }
        smax_pv(s, kt == thi, wl, q4, mA, lA, oA, vf);
      }
      if (kt <= tlo){
        fx4 s[4] = {};
#pragma unroll
        for (int tl = 0; tl < 4; tl++){
          s[tl] = __builtin_amdgcn_mfma_f32_16x16x32_bf16(kf0[tl], qB0, s[tl], 0,0,0);
          s[tl] = __builtin_amdgcn_mfma_f32_16x16x32_bf16(kf1[tl], qB1, s[tl], 0,0,0);
        }
        smax_pv(s, kt == tlo, wl, q4, mB, lB, oB, vf);
      }
    }
    __syncthreads();
  }

  float* F = (float*)SB;
  if (g == 1){
    float* fa = F + (((wi*2 + 0)*64 + l)*18);
#pragma unroll
    for (int nt = 0; nt < 4; nt++)
#pragma unroll
      for (int j = 0; j < 4; j++) fa[nt*4 + j] = oA[nt][j];
    fa[16] = mA; fa[17] = lA;
    float* fb = F + (((wi*2 + 1)*64 + l)*18);
#pragma unroll
    for (int nt = 0; nt < 4; nt++)
#pragma unroll
      for (int j = 0; j < 4; j++) fb[nt*4 + j] = oB[nt][j];
    fb[16] = mB; fb[17] = lB;
  }
  __syncthreads();
  if (g == 0){
    {
      const float* fa = F + (((wi*2 + 0)*64 + l)*18);
      float m1 = fa[16], l1 = fa[17];
      float mM = fmaxf(mA, m1);
      float a0 = exp2f(mA - mM), a1 = exp2f(m1 - mM);
      lA = lA*a0 + l1*a1;
#pragma unroll
      for (int nt = 0; nt < 4; nt++)
#pragma unroll
        for (int j = 0; j < 4; j++) oA[nt][j] = oA[nt][j]*a0 + fa[nt*4+j]*a1;
    }
    {
      const float* fb = F + (((wi*2 + 1)*64 + l)*18);
      float m1 = fb[16], l1 = fb[17];
      float mM = fmaxf(mB, m1);
      float a0 = exp2f(mB - mM), a1 = exp2f(m1 - mM);
      lB = lB*a0 + l1*a1;
#pragma unroll
      for (int nt = 0; nt < 4; nt++)
#pragma unroll
        for (int j = 0; j < 4; j++) oB[nt][j] = oB[nt][j]*a0 + fb[nt*4+j]*a1;
    }
    {
      float inv = 1.0f / lA;
      unsigned short* dst = ao + ((size_t)(b*SEQ + thi*64 + wl))*HID + h*64;
#pragma unroll
      for (int nt = 0; nt < 4; nt++){
        s16x4 ov;
        ov[0] = (short)f2b(oA[nt][0]*inv); ov[1] = (short)f2b(oA[nt][1]*inv);
        ov[2] = (short)f2b(oA[nt][2]*inv); ov[3] = (short)f2b(oA[nt][3]*inv);
        *(s16x4*)(dst + nt*16 + q4*4) = ov;
      }
    }
    {
      float inv = 1.0f / lB;
      unsigned short* dst = ao + ((size_t)(b*SEQ + tlo*64 + wl))*HID + h*64;
#pragma unroll
      for (int nt = 0; nt < 4; nt++){
        s16x4 ov;
        ov[0] = (short)f2b(oB[nt][0]*inv); ov[1] = (short)f2b(oB[nt][1]*inv);
        ov[2] = (short)f2b(oB[nt][2]*inv); ov[3] = (short)f2b(oB[nt][3]*inv);
        *(s16x4*)(dst + nt*16 + q4*4) = ov;
      }
    }
  }
}

// ---------------- output projection GEMM: dbuf gll16 pipeline -> fp32 ----------------
// A = attn bf16 [4096,896], B = Wo bf16 [896,896]. grid (64, 7), block 256.
__global__ __launch_bounds__(256) void out_gemm_kernel(
    const unsigned short* __restrict__ A, const unsigned short* __restrict__ Bw,
    float* __restrict__ out)
{
  __shared__ short As[2][64*64];
  __shared__ short Bs[2][128*64];
  const int tid = threadIdx.x;
  const int bm = blockIdx.x, bn = blockIdx.y;
  const int w = tid >> 6, l = tid & 63, l15 = l & 15, q4 = l >> 4;
  const int wm = w >> 1, wn = w & 1;
  const int lr = l >> 3;
  const int cbg = (l & 7) ^ lr;
  const int sw = l15 & 7;

  fx4 acc[2][4] = {};

  const unsigned short* Ag = A  + (size_t)(bm*64)*HID;
  const unsigned short* Bg = Bw + (size_t)(bn*128)*HID;

  auto issue = [&](int kt, int buf){
    const int kc = kt*64 + cbg*8;
#pragma unroll
    for (int p = 0; p < 2; p++){
      int c = p*4 + w;
      gll16(Ag + (size_t)(c*8 + lr)*HID + kc, &As[buf][c*512]);
    }
#pragma unroll
    for (int p = 0; p < 4; p++){
      int c = p*4 + w;
      gll16(Bg + (size_t)(c*8 + lr)*HID + kc, &Bs[buf][c*512]);
    }
  };

  issue(0, 0);
  for (int kt = 0; kt < 14; kt++){
    const int cur = kt & 1;
    if (kt < 13){
      issue(kt+1, cur^1);
      asm volatile("s_waitcnt vmcnt(6)\n\ts_barrier" ::: "memory");
    } else {
      asm volatile("s_waitcnt vmcnt(0)\n\ts_barrier" ::: "memory");
    }
#pragma unroll
    for (int ks = 0; ks < 2; ks++){
      bf16x8 af[2], bf[4];
#pragma unroll
      for (int mt = 0; mt < 2; mt++){
        int r = wm*32 + mt*16 + l15;
        af[mt] = *(bf16x8*)&As[cur][r*64 + ((ks*4 + q4) ^ sw)*8];
      }
#pragma unroll
      for (int nt = 0; nt < 4; nt++){
        int r = wn*64 + nt*16 + l15;
        bf[nt] = *(bf16x8*)&Bs[cur][r*64 + ((ks*4 + q4) ^ sw)*8];
      }
#pragma unroll
      for (int mt = 0; mt < 2; mt++)
#pragma unroll
        for (int nt = 0; nt < 4; nt++)
          acc[mt][nt] = __builtin_amdgcn_mfma_f32_16x16x32_bf16(af[mt], bf[nt], acc[mt][nt], 0,0,0);
    }
    asm volatile("s_barrier" ::: "memory");
  }

#pragma unroll
  for (int mt = 0; mt < 2; mt++)
#pragma unroll
    for (int j = 0; j < 4; j++){
      int grow = bm*64 + wm*32 + mt*16 + q4*4 + j;
      float* dst = out + (size_t)grow*HID + bn*128 + wn*64;
#pragma unroll
      for (int nt = 0; nt < 4; nt++)
        dst[nt*16 + l15] = acc[mt][nt][j];
    }
}

extern "C" void kernel_launch(void* const* d_in, const int* in_sizes, int n_in,
                              void* d_out, int out_size, void* d_ws, size_t ws_size,
                              hipStream_t stream)
{
  const float* hidden = (const float*)d_in[0];
  const int*   pos    = (const int*)d_in[1];
  const float* Wq = (const float*)d_in[2]; const float* bq = (const float*)d_in[3];
  const float* Wk = (const float*)d_in[4]; const float* bk = (const float*)d_in[5];
  const float* Wv = (const float*)d_in[6]; const float* bv = (const float*)d_in[7];
  const float* Wo = (const float*)d_in[8];

  unsigned short* qws   = (unsigned short*)d_ws;                       // (B,NH,S,64) bf16 (Q pre-scaled)
  unsigned short* kws   = qws   + (size_t)BT*NH*SEQ*64;                // (B,NKV,S,64) bf16
  unsigned short* vtws  = kws   + (size_t)BT*NKV*SEQ*64;               // (B,NKV,S/64,64,64) f16
  unsigned short* wqkv  = vtws  + (size_t)BT*NKV*SEQ*64;               // (1152,896) bf16
  unsigned short* wo16  = wqkv  + (size_t)1152*HID;                    // (896,896) bf16
  unsigned short* h16   = wo16  + (size_t)HID*HID;                     // (4096,896) bf16: attn-out
  float2*         tab   = (float2*)(h16 + (size_t)NTOK*HID);           // (2048,32) rope table

  const int nwq  = HID*HID;
  const int nwkv = 2*64*HID;

  cvt_kernel<<<dim3(448, 5), 256, 0, stream>>>(
      Wq, Wk, Wv, Wo,
      wqkv, wqkv + nwq, wqkv + nwq + nwkv, wo16,
      nwq, nwkv, nwkv, nwq, tab);

  qkv_gemm_kernel<<<dim3(NTOK/64, 9), 256, 0, stream>>>(
      hidden, wqkv, bq, bk, bv, pos, tab, qws, kws, vtws);

  attn_kernel<<<dim3(16, NH, BT), 512, 0, stream>>>(qws, kws, vtws, h16);

  out_gemm_kernel<<<dim3(NTOK/64, 7), 256, 0, stream>>>(h16, wo16, (float*)d_out);
}